// Round 29
// baseline (226.832 us; speedup 1.0000x reference)
//
#include <hip/hip_runtime.h>
#include <math.h>

#define BB 4
#define NN 4096
#define KK 16
#define CIN 32
#define BN_INV 0.9999950000375f

#define RS 32    // candidate ranges per query (128 candidates each)
#define PK 8     // prefilter top-K per range
#define TSL 16   // per-wave-slice forwarded top keys
#define NSURV 24 // global fp32-key survivors reranked in fp64
#define NSL 8    // wave-slices in knn_select (4 ranges each)

typedef float f32x2 __attribute__((ext_vector_type(2)));
typedef float f32x16v __attribute__((ext_vector_type(16)));
typedef short bf16x8 __attribute__((ext_vector_type(8)));
typedef unsigned long long u64;

__device__ __forceinline__ u64 u64min(u64 a, u64 b) { return a < b ? a : b; }
__device__ __forceinline__ u64 u64max(u64 a, u64 b) { return a > b ? a : b; }
__device__ __forceinline__ unsigned short f2bf(float x) {
    unsigned u = __float_as_uint(x);
    unsigned r = u + 0x7FFFu + ((u >> 16) & 1u);  // RNE
    return (unsigned short)(r >> 16);
}

// Merge sorted pair {keys of DX,DY} into sorted-desc K[0..7] keeping top-8.
#define KMERGE2(K, DX, DY, MK0, MK1)                                                  \
    {                                                                                 \
        unsigned uA_ = ~__float_as_uint(DX);                                          \
        unsigned uB_ = ~__float_as_uint(DY);                                          \
        unsigned kA_ = (uA_ & 0xFFFFF000u) | (unsigned)(MK0);                         \
        unsigned kB_ = (uB_ & 0xFFFFF000u) | (unsigned)(MK1);                         \
        unsigned P0_ = __builtin_elementwise_max(kA_, kB_);                           \
        unsigned P1_ = __builtin_elementwise_min(kA_, kB_);                           \
        unsigned mp0_[7], mp1_[6];                                                    \
        _Pragma("unroll")                                                             \
        for (int j_ = 0; j_ < 7; ++j_) mp0_[j_] = __builtin_elementwise_min(K[j_], P0_); \
        _Pragma("unroll")                                                             \
        for (int j_ = 0; j_ < 6; ++j_) mp1_[j_] = __builtin_elementwise_min(K[j_], P1_); \
        unsigned R_[8];                                                               \
        R_[0] = __builtin_elementwise_max(K[0], P0_);                                 \
        R_[1] = __builtin_elementwise_max(__builtin_elementwise_max(K[1], mp0_[0]), P1_); \
        _Pragma("unroll")                                                             \
        for (int j_ = 2; j_ < 8; ++j_)                                                \
            R_[j_] = __builtin_elementwise_max(                                       \
                __builtin_elementwise_max(K[j_], mp0_[j_ - 1]), mp1_[j_ - 2]);        \
        _Pragma("unroll")                                                             \
        for (int j_ = 0; j_ < 8; ++j_) K[j_] = R_[j_];                                \
    }

// ---------------- P1 (+P0 folded): transpose + norms + bf16 splits + weights ----------
__global__ void p1_transpose(const float* __restrict__ f, float* __restrict__ pT,
                             float* __restrict__ sq32, double* __restrict__ sq64,
                             unsigned short* __restrict__ pTh,
                             unsigned short* __restrict__ pTl,
                             const float* __restrict__ W1, const float* __restrict__ W2,
                             const float* __restrict__ W3, const float* __restrict__ W4,
                             const float* __restrict__ W5,
                             const float* __restrict__ g1, const float* __restrict__ g2,
                             const float* __restrict__ g3, const float* __restrict__ g4,
                             const float* __restrict__ g5,
                             float* __restrict__ Aw, float* __restrict__ Bw,
                             float* __restrict__ w1d, float* __restrict__ W2s,
                             float* __restrict__ W3p, float* __restrict__ W4p,
                             unsigned short* __restrict__ W5b) {
    int t = threadIdx.x;
    if (blockIdx.x == 0) {  // weight prep (former p0)
        for (int i = t; i < 64 * 32; i += 256) {
            int o = i >> 5, c = i & 31;
            float s = g1[o] * BN_INV;
            Aw[i] = (W1[o * 128 + c] - W1[o * 128 + 64 + c]) * s;
            Bw[i] = (W1[o * 128 + 32 + c] + W1[o * 128 + 64 + c]) * s;
        }
        if (t < 64) {
            float s = 0.f;
            for (int c = 96; c < 128; ++c) s += W1[t * 128 + c];
            w1d[t] = s * (g1[t] * BN_INV);
        }
        for (int i = t; i < 192; i += 256) W2s[i] = W2[i] * (g2[i / 64] * BN_INV);
        for (int i = t; i < 32 * 14; i += 256) {
            int r = i / 14, j = i - r * 14;
            W3p[i] = (j < 13) ? W3[r * 13 + j] * (g3[r] * BN_INV) : 0.f;
            W4p[i] = (j < 13) ? W4[r * 13 + j] * (g4[r] * BN_INV) : 0.f;
        }
        for (int i = t; i < 3072; i += 256)
            W5b[i] = f2bf(W5[i] * (g5[i / 96] * BN_INV));
    }
    int g = blockIdx.x * 256 + t;  // b*N + n
    int b = g >> 12, n = g & (NN - 1);
    float v[CIN];
#pragma unroll
    for (int c = 0; c < CIN; ++c) v[c] = f[(b * CIN + c) * NN + n];
#pragma unroll
    for (int c = 0; c < CIN; ++c) pT[(size_t)g * CIN + c] = v[c];
    // bf16 hi/lo split for the MFMA prefilter
#pragma unroll
    for (int c = 0; c < CIN; ++c) {
        unsigned short h = f2bf(v[c]);
        float hf = __uint_as_float((unsigned)h << 16);
        pTh[(size_t)g * CIN + c] = h;
        pTl[(size_t)g * CIN + c] = f2bf(v[c] - hf);
    }
    float s32 = 0.f;
#pragma unroll
    for (int c = 0; c < CIN; ++c) s32 = fmaf(v[c], v[c], s32);
    sq32[g] = s32;
    // sequential fp64 chain — must match knn_select's rerank chains
    double s64 = 0.0;
#pragma unroll
    for (int c = 0; c < CIN; ++c) s64 = fma((double)v[c], (double)v[c], s64);
    sq64[g] = s64;
}

// ---------------- KNN prefilter (MFMA) + fused p2 slice (blockIdx.y == 4) -------------
__global__ __launch_bounds__(256, 8) void knn_prefilter(
        const unsigned short* __restrict__ pTh,
        const unsigned short* __restrict__ pTl,
        const float* __restrict__ sq32,
        unsigned* __restrict__ pkey,
        const float* __restrict__ pT,
        const float* __restrict__ Aw,
        const float* __restrict__ Bw,
        float* __restrict__ ctrA,
        float* __restrict__ nbrB) {
    __shared__ float sAB[2][2048];  // 16 KB, used only by the p2 slice
    if (blockIdx.y == 4) {
        // p2: per-point projections ctrA = A*p, nbrB = B*p (pre-scaled weights)
        float* sA = sAB[0];
        float* sB = sAB[1];
        for (int i = threadIdx.x; i < 2048; i += 256) {
            int o = i >> 5, c = i & 31;
            sA[c * 64 + o] = Aw[i];
            sB[c * 64 + o] = Bw[i];
        }
        __syncthreads();
#pragma unroll 1
        for (int it = 0; it < 8; ++it) {
            int g = (blockIdx.x * 8 + it) * 256 + threadIdx.x;  // (b*N+n)*64 + o
            int o = g & 63;
            int pn = g >> 6;
            const float* p = pT + (size_t)pn * 32;
            float a = 0.f, bb = 0.f;
#pragma unroll
            for (int c = 0; c < 32; ++c) {
                float pv = p[c];
                a = fmaf(sA[c * 64 + o], pv, a);
                bb = fmaf(sB[c * 64 + o], pv, bb);
            }
            ctrA[g] = a;
            nbrB[g] = bb;
        }
        return;
    }

    int lane = threadIdx.x & 63;
    int wave = threadIdx.x >> 6;        // 0..3
    int ws = wave + 4 * blockIdx.y;     // range slot 0..15 (2 ranges of 128 each)
    int qtile = blockIdx.x;             // 0..511
    int pn = qtile * 32 + (lane & 31);  // this lane's query (global point id)
    int b = pn >> 12;
    int bbase = b << 12;
    int koff = (lane >> 5) * 8;

    const unsigned short* qh = pTh + (size_t)pn * 32;
    const unsigned short* ql = pTl + (size_t)pn * 32;
    bf16x8 bh0 = *(const bf16x8*)(qh + koff);
    bf16x8 bh1 = *(const bf16x8*)(qh + 16 + koff);
    bf16x8 bl0 = *(const bf16x8*)(ql + koff);
    bf16x8 bl1 = *(const bf16x8*)(ql + 16 + koff);
    float sqq = sq32[pn];

    for (int r = ws * 2; r < ws * 2 + 2; ++r) {
        unsigned key[PK];
#pragma unroll
        for (int i = 0; i < PK; ++i) key[i] = 0u;
#pragma unroll
        for (int tile = 0; tile < 4; ++tile) {
            int cb = r * 128 + tile * 32;                // candidate base within batch
            int crow = bbase + cb + (lane & 31);
            const unsigned short* ah = pTh + (size_t)crow * 32;
            const unsigned short* al = pTl + (size_t)crow * 32;
            bf16x8 a_h0 = *(const bf16x8*)(ah + koff);
            bf16x8 a_h1 = *(const bf16x8*)(ah + 16 + koff);
            bf16x8 a_l0 = *(const bf16x8*)(al + koff);
            bf16x8 a_l1 = *(const bf16x8*)(al + 16 + koff);
            f32x16v acc = {};
            acc = __builtin_amdgcn_mfma_f32_32x32x16_bf16(a_h0, bh0, acc, 0, 0, 0);
            acc = __builtin_amdgcn_mfma_f32_32x32x16_bf16(a_h1, bh1, acc, 0, 0, 0);
            acc = __builtin_amdgcn_mfma_f32_32x32x16_bf16(a_h0, bl0, acc, 0, 0, 0);
            acc = __builtin_amdgcn_mfma_f32_32x32x16_bf16(a_h1, bl1, acc, 0, 0, 0);
            acc = __builtin_amdgcn_mfma_f32_32x32x16_bf16(a_l0, bh0, acc, 0, 0, 0);
            acc = __builtin_amdgcn_mfma_f32_32x32x16_bf16(a_l1, bh1, acc, 0, 0, 0);
            int rb = bbase + cb + 4 * (lane >> 5);
            float4 s0 = *(const float4*)(sq32 + rb);
            float4 s1 = *(const float4*)(sq32 + rb + 8);
            float4 s2 = *(const float4*)(sq32 + rb + 16);
            float4 s3 = *(const float4*)(sq32 + rb + 24);
            float sarr[16] = {s0.x, s0.y, s0.z, s0.w, s1.x, s1.y, s1.z, s1.w,
                              s2.x, s2.y, s2.z, s2.w, s3.x, s3.y, s3.z, s3.w};
#pragma unroll
            for (int j = 0; j < 16; j += 2) {
                float d0 = fmaf(2.f, acc[j], -(sqq + sarr[j]));
                float d1 = fmaf(2.f, acc[j + 1], -(sqq + sarr[j + 1]));
                int mk0 = 4095 - (cb + (j & 3) + 8 * (j >> 2) + 4 * (lane >> 5));
                KMERGE2(key, d0, d1, mk0, mk0 - 1)
            }
        }
        unsigned ok[PK];
#pragma unroll
        for (int i = 0; i < PK; ++i) ok[i] = __shfl(key[i], lane ^ 32, 64);
        unsigned R[PK];
#pragma unroll
        for (int j = 0; j < PK; ++j) {
            unsigned m = __builtin_elementwise_max(key[j], ok[j]);
#pragma unroll
            for (int a = 0; a < j; ++a)
                m = __builtin_elementwise_max(
                    m, __builtin_elementwise_min(key[a], ok[j - 1 - a]));
            R[j] = m;
        }
        if (lane < 32) {
#pragma unroll
            for (int i = 0; i < PK; ++i)
                pkey[(size_t)(r * PK + i) * (BB * NN) + pn] = R[i];
        }
    }
}

// ---------------- KNN select: 512 thr, 8 slices of 4 ranges; -> top-24 -> fp64 ---------
__global__ __launch_bounds__(512) void knn_select(const float* __restrict__ pT,
                                                  const double* __restrict__ sq64,
                                                  const unsigned* __restrict__ pkey,
                                                  int* __restrict__ fidx,
                                                  float* __restrict__ fdist) {
    __shared__ unsigned sA[NSL][64][TSL];   // 32 KB
    __shared__ unsigned sCand[64][NSURV];   // 6 KB
    __shared__ u64 sKl[NSL][64][3];         // 12 KB
    int tid = threadIdx.x;
    int q = tid & 63;
    int w = tid >> 6;                       // 0..7
    int n = blockIdx.x * 64 + q;
    int b = n >> 12;

    // Phase A: scan ranges [4w,4w+4) -> top-TSL fp32 keys (coalesced, early-break)
    unsigned sk[TSL];
#pragma unroll
    for (int i = 0; i < TSL; ++i) sk[i] = 0u;
#pragma unroll 1
    for (int r = w * 4; r < w * 4 + 4; ++r) {
        unsigned kv[PK];
#pragma unroll
        for (int k = 0; k < PK; ++k)
            kv[k] = pkey[(size_t)(r * PK + k) * (BB * NN) + n];
        for (int k = 0; k < PK; ++k) {
            unsigned cv = kv[k];
            if (__all(cv <= sk[TSL - 1])) break;  // range keys sorted desc
#pragma unroll
            for (int j = 0; j < TSL; ++j) {
                unsigned vj = sk[j];
                sk[j] = __builtin_elementwise_max(cv, vj);
                cv = __builtin_elementwise_min(cv, vj);
            }
        }
    }
#pragma unroll
    for (int i = 0; i < TSL; ++i) sA[w][q][i] = sk[i];
    __syncthreads();

    // Phase B: merge NSL sorted-TSL lists -> global top-NSURV candidate ids
    if (tid < 64) {
        unsigned R[NSURV];
#pragma unroll
        for (int i = 0; i < NSURV; ++i) R[i] = (i < TSL) ? sA[0][tid][i] : 0u;
#pragma unroll 1
        for (int wv = 1; wv < NSL; ++wv) {
            unsigned L[TSL];
#pragma unroll
            for (int i = 0; i < TSL; ++i) L[i] = sA[wv][tid][i];
            unsigned Rn[NSURV];
#pragma unroll
            for (int j = 0; j < NSURV; ++j) {
                unsigned m = R[j];
                if (j < TSL) m = __builtin_elementwise_max(m, L[j]);
#pragma unroll
                for (int t = 0; t < NSURV; ++t) {
                    if (t < j && t < TSL) {
                        m = __builtin_elementwise_max(
                            m, __builtin_elementwise_min(R[j - 1 - t], L[t]));
                    }
                }
                Rn[j] = m;
            }
#pragma unroll
            for (int j = 0; j < NSURV; ++j) R[j] = Rn[j];
        }
#pragma unroll
        for (int i = 0; i < NSURV; ++i) sCand[tid][i] = 4095u - (R[i] & 0xFFFu);
    }
    __syncthreads();

    // Phase C: fp64 rerank — thread (q,w) handles survivors w, w+8, w+16 (3 each)
    {
        const float* pb = pT + ((size_t)(b << 12)) * 32;
        const double* sqb = sq64 + (b << 12);
        double qv[32];
        const float4* q4 = (const float4*)(pT + (size_t)n * 32);
#pragma unroll
        for (int c4 = 0; c4 < 8; ++c4) {
            float4 t = q4[c4];
            qv[4 * c4] = (double)t.x; qv[4 * c4 + 1] = (double)t.y;
            qv[4 * c4 + 2] = (double)t.z; qv[4 * c4 + 3] = (double)t.w;
        }
        double sqn = 0.0;
#pragma unroll
        for (int c = 0; c < 32; ++c) sqn = fma(qv[c], qv[c], sqn);

        u64 kl[3];
#pragma unroll
        for (int i = 0; i < 3; ++i) kl[i] = 0ull;
#pragma unroll
        for (int i = 0; i < 3; ++i) {
            int m = (int)sCand[q][w + NSL * i];
            const float4* row = (const float4*)(pb + (size_t)m * 32);
            double dot = 0.0;
#pragma unroll
            for (int c4 = 0; c4 < 8; ++c4) {
                float4 t = row[c4];
                dot = fma((double)t.x, qv[4 * c4], dot);
                dot = fma((double)t.y, qv[4 * c4 + 1], dot);
                dot = fma((double)t.z, qv[4 * c4 + 2], dot);
                dot = fma((double)t.w, qv[4 * c4 + 3], dot);
            }
            double d = 2.0 * dot - sqn - sqb[m];  // self -> exactly 0
            long long bits = __double_as_longlong(d);
            u64 m64 = (bits < 0) ? ~(u64)bits : ((u64)bits | 0x8000000000000000ull);
            u64 cv = (m64 & ~0xFFFull) | (unsigned)m;  // pack idx in low 12 bits
#pragma unroll
            for (int j = 0; j < 3; ++j) {
                u64 vj = kl[j];
                kl[j] = u64max(cv, vj);
                cv = u64min(cv, vj);
            }
        }
#pragma unroll
        for (int i = 0; i < 3; ++i) sKl[w][q][i] = kl[i];
    }
    __syncthreads();

    // Phase D: merge NSL sorted-3 u64 lists -> exact top-16; write outputs
    if (tid < 64) {
        u64 R[16];
#pragma unroll
        for (int i = 0; i < 16; ++i) R[i] = (i < 3) ? sKl[0][tid][i] : 0ull;
#pragma unroll 1
        for (int wv = 1; wv < NSL; ++wv) {
            u64 L[3];
#pragma unroll
            for (int i = 0; i < 3; ++i) L[i] = sKl[wv][tid][i];
            u64 Rn[16];
#pragma unroll
            for (int j = 0; j < 16; ++j) {
                u64 m = R[j];
                if (j < 3) m = u64max(m, L[j]);
#pragma unroll
                for (int t = 0; t < 3; ++t) {
                    if (t < j) m = u64max(m, u64min(R[j - 1 - t], L[t]));
                }
                Rn[j] = m;
            }
#pragma unroll
            for (int j = 0; j < 16; ++j) R[j] = Rn[j];
        }
        int nq = blockIdx.x * 64 + tid;
#pragma unroll
        for (int i = 0; i < 16; ++i) {
            u64 m64 = R[i];
            long long bits = (m64 & 0x8000000000000000ull)
                                 ? (long long)(m64 ^ 0x8000000000000000ull)
                                 : (long long)~m64;
            fdist[(size_t)nq * 16 + i] = (float)__longlong_as_double(bits);
            fidx[(size_t)nq * 16 + i] = (int)(m64 & 0xFFFull);
        }
    }
}

// ---------------- Fused pipeline: 64-thr blocks (1 wave); W5 via MFMA 3-phase LDS ------
__global__ __launch_bounds__(64, 4) void fuse_kernel(
    const float* __restrict__ coords, const float* __restrict__ feat,
    const int* __restrict__ knn_idx, const float* __restrict__ knn_dist,
    const float* __restrict__ W2s, const float* __restrict__ W3p,
    const float* __restrict__ W4p, const unsigned short* __restrict__ W5b,
    const float* __restrict__ b1, const float* __restrict__ b2,
    const float* __restrict__ b3, const float* __restrict__ b4,
    const float* __restrict__ b5,
    const float* __restrict__ ctrA, const float* __restrict__ nbrB,
    const float* __restrict__ w1d, const int* __restrict__ fidx,
    const float* __restrict__ fdist, float* __restrict__ out) {
    __shared__ unsigned short xbuf[64][36];  // 4.6 KB: 32-col phase tile (wave-local)
    int ln = threadIdx.x;                    // 0..63, one wave per block
    int g = blockIdx.x * 64 + ln;
    int k = g & 15;
    int n = (g >> 4) & (NN - 1);
    int b = g >> 16;
    int pn = b * NN + n;

    // coalesced per-(n,k) gathers
    int fnb = fidx[(size_t)pn * 16 + k];
    float fd = fdist[(size_t)pn * 16 + k];
    int cnb = knn_idx[(size_t)pn * 16 + k];
    float kd = knn_dist[(size_t)pn * 16 + k];
    const float4* nB4 = (const float4*)(nbrB + ((size_t)b * NN + fnb) * 64);
    const float4* cA4 = (const float4*)(ctrA + (size_t)pn * 64);
    float cq[3], cn_[3];
#pragma unroll
    for (int j = 0; j < 3; ++j) cq[j] = coords[(size_t)pn * 3 + j];
#pragma unroll
    for (int j = 0; j < 3; ++j) cn_[j] = coords[((size_t)b * NN + cnb) * 3 + j];

    // features_knn (64): fk = max(v, 0.2v), v = cA' + nB' + w1d'*fd + b1 (scales pre-folded)
    const f32x2* wd2 = (const f32x2*)w1d;
    const f32x2* b12 = (const f32x2*)b1;
    f32x2 fdp = (f32x2){fd, fd};
    f32x2 pt2 = (f32x2){0.2f, 0.2f};
    f32x2 fkp[32];
#pragma unroll
    for (int half = 0; half < 2; ++half) {
        float4 nbh[8];
#pragma unroll
        for (int i = 0; i < 8; ++i) nbh[i] = nB4[8 * half + i];  // batched gather
#pragma unroll
        for (int j = 0; j < 8; ++j) {
            int o4 = 8 * half + j;
            float4 nb = nbh[j];
            float4 ca = cA4[o4];
            f32x2 s01 = (f32x2){ca.x, ca.y} + (f32x2){nb.x, nb.y};
            f32x2 s23 = (f32x2){ca.z, ca.w} + (f32x2){nb.z, nb.w};
            f32x2 v0 = __builtin_elementwise_fma(wd2[2 * o4 + 0], fdp, s01) + b12[2 * o4 + 0];
            f32x2 v1 = __builtin_elementwise_fma(wd2[2 * o4 + 1], fdp, s23) + b12[2 * o4 + 1];
            fkp[2 * o4 + 0] = __builtin_elementwise_max(v0, v0 * pt2);
            fkp[2 * o4 + 1] = __builtin_elementwise_max(v1, v1 * pt2);
        }
    }

    // batch-issue feat loads early
    float fadd[32];
#pragma unroll
    for (int c = 0; c < 32; ++c) fadd[c] = feat[((size_t)b * 32 + c) * NN + n];

    // features_offset (3) = elu(W2s . fk + b2); 4-acc ILP dot
    f32x2 cpp[7];
    float pe[3];
#pragma unroll
    for (int j = 0; j < 3; ++j) {
        const f32x2* w2r = (const f32x2*)(W2s + j * 64);
        f32x2 a0 = (f32x2){0.f, 0.f}, a1 = (f32x2){0.f, 0.f};
        f32x2 a2 = (f32x2){0.f, 0.f}, a3 = (f32x2){0.f, 0.f};
#pragma unroll
        for (int i = 0; i < 8; ++i) {
            a0 = __builtin_elementwise_fma(w2r[4 * i + 0], fkp[4 * i + 0], a0);
            a1 = __builtin_elementwise_fma(w2r[4 * i + 1], fkp[4 * i + 1], a1);
            a2 = __builtin_elementwise_fma(w2r[4 * i + 2], fkp[4 * i + 2], a2);
            a3 = __builtin_elementwise_fma(w2r[4 * i + 3], fkp[4 * i + 3], a3);
        }
        f32x2 ap = (a0 + a1) + (a2 + a3);
        float t = (ap.x + ap.y) + b2[j];
        t = t > 0.f ? t : __expf(t) - 1.f;
        pe[j] = t + cq[j];
    }
    cpp[0] = (f32x2){cq[0], cq[1]};
    cpp[1] = (f32x2){cq[2], cn_[0]};
    cpp[2] = (f32x2){cn_[1], cn_[2]};
    cpp[3] = (f32x2){cq[0] - cn_[0], cq[1] - cn_[1]};
    cpp[4] = (f32x2){cq[2] - cn_[2], kd};
    cpp[5] = (f32x2){pe[0], pe[1]};
    cpp[6] = (f32x2){pe[2], 0.f};

    // point_offset -> features_e ; out_point (unrolled: fep writes must be static)
    size_t outbase = (((size_t)b * 64) * NN + n) * 16 + k;  // c stride NN*16
    f32x2 fep[16];
#pragma unroll
    for (int c2 = 0; c2 < 16; ++c2) {
        float fv[2];
#pragma unroll
        for (int h = 0; h < 2; ++h) {
            int c = 2 * c2 + h;
            const f32x2* w3r = (const f32x2*)(W3p + c * 14);
            const f32x2* w4r = (const f32x2*)(W4p + c * 14);
            f32x2 a3p = (f32x2){0.f, 0.f}, a4p = (f32x2){0.f, 0.f};
#pragma unroll
            for (int j = 0; j < 7; ++j) {
                a3p = __builtin_elementwise_fma(w3r[j], cpp[j], a3p);
                a4p = __builtin_elementwise_fma(w4r[j], cpp[j], a4p);
            }
            float po = (a3p.x + a3p.y) + b3[c];
            po = po > 0.f ? po : __expf(po) - 1.f;
            fv[h] = po + fadd[c];
            float op = (a4p.x + a4p.y) + b4[c];
            op = op > 0.f ? op : __expf(op) - 1.f;
            out[outbase + (size_t)c * (NN * 16)] = op;
        }
        fep[c2] = (f32x2){fv[0], fv[1]};
    }

    // W5 via MFMA in 3 wave-local phases (one wave per block; lockstep LDS, no barrier).
    {
        int koff = (ln >> 5) * 8;
        unsigned* row32 = (unsigned*)&xbuf[ln][0];
        f32x16v acc0 = {}, acc1 = {};
#pragma unroll
        for (int ph = 0; ph < 3; ++ph) {
#pragma unroll
            for (int i = 0; i < 16; ++i) {
                f32x2 src = (ph == 0) ? fkp[i] : (ph == 1) ? fkp[16 + i] : fep[i];
                unsigned u0 = __float_as_uint(src.x);
                unsigned u1 = __float_as_uint(src.y);
                row32[i] = (u0 >> 16) | (u1 & 0xFFFF0000u);
            }
#pragma unroll
            for (int c2 = 0; c2 < 2; ++c2) {
                int ch = ph * 2 + c2;
                bf16x8 aw = *(const bf16x8*)(W5b + (ln & 31) * 96 + ch * 16 + koff);
                bf16x8 bx0 = *(const bf16x8*)(&xbuf[ln & 31][c2 * 16 + koff]);
                bf16x8 bx1 = *(const bf16x8*)(&xbuf[32 + (ln & 31)][c2 * 16 + koff]);
                acc0 = __builtin_amdgcn_mfma_f32_32x32x16_bf16(aw, bx0, acc0, 0, 0, 0);
                acc1 = __builtin_amdgcn_mfma_f32_32x32x16_bf16(aw, bx1, acc1, 0, 0, 0);
            }
        }
#pragma unroll
        for (int tile = 0; tile < 2; ++tile) {
            int p = tile * 32 + (ln & 31);
            int gg = blockIdx.x * 64 + p;
            int kk = gg & 15;
            int nn2 = (gg >> 4) & (NN - 1);
            int bb2 = gg >> 16;
            size_t obase = (((size_t)bb2 * 64 + 32) * NN + nn2) * 16 + kk;
            const f32x16v& acc = tile ? acc1 : acc0;
#pragma unroll
            for (int j = 0; j < 16; ++j) {
                int c = (j & 3) + 8 * (j >> 2) + 4 * (ln >> 5);
                float v = acc[j] + b5[c];
                v = v > 0.f ? v : __expf(v) - 1.f;
                out[obase + (size_t)c * (NN * 16)] = v;
            }
        }
    }
}

extern "C" void kernel_launch(void* const* d_in, const int* in_sizes, int n_in,
                              void* d_out, int out_size, void* d_ws, size_t ws_size,
                              hipStream_t stream) {
    const float* coords   = (const float*)d_in[0];
    const float* features = (const float*)d_in[1];
    const int*   knn_idx  = (const int*)d_in[2];
    const float* knn_dist = (const float*)d_in[3];
    const float* W1 = (const float*)d_in[4];
    const float* W2 = (const float*)d_in[5];
    const float* W3 = (const float*)d_in[6];
    const float* W4 = (const float*)d_in[7];
    const float* W5 = (const float*)d_in[8];
    const float* g1 = (const float*)d_in[9];
    const float* b1 = (const float*)d_in[10];
    const float* g2 = (const float*)d_in[11];
    const float* b2 = (const float*)d_in[12];
    const float* g3 = (const float*)d_in[13];
    const float* b3 = (const float*)d_in[14];
    const float* g4 = (const float*)d_in[15];
    const float* b4 = (const float*)d_in[16];
    const float* g5 = (const float*)d_in[17];
    const float* b5 = (const float*)d_in[18];
    float* out = (float*)d_out;

    // workspace layout (float slots)
    float*  pT    = (float*)d_ws;                  // 524288
    float*  sq32  = pT + BB * NN * 32;             // 16384
    double* sq64  = (double*)(sq32 + BB * NN);     // 16384 doubles (32768 slots)
    float*  fdist = (float*)(sq64 + BB * NN);      // 262144
    int*    fidx  = (int*)(fdist + BB * NN * 16);  // 262144
    float*  Aw    = (float*)(fidx + BB * NN * 16); // 2048
    float*  Bw    = Aw + 2048;                     // 2048
    float*  w1d   = Bw + 2048;                     // 64
    float*  W3p   = w1d + 64;                      // 448 (pad to 512)
    float*  W4p   = W3p + 512;                     // 448 (pad to 512)
    float*  W2s   = W4p + 512;                     // 192 (pad to 256)
    unsigned short* W5b = (unsigned short*)(W2s + 256);  // 3072 u16 (1536 slots)
    float*  ctrA  = W2s + 256 + 1536;              // B*N*64 = 1048576
    float*  nbrB  = ctrA + BB * NN * 64;           // B*N*64 = 1048576
    unsigned short* pTh = (unsigned short*)(nbrB + BB * NN * 64);  // B*N*32 u16
    unsigned short* pTl = pTh + (size_t)BB * NN * 32;              // B*N*32 u16
    // scratch in d_out (67.1 MB): pkey [RS*PK][B*N] u32 = 16.8 MB (prefilter -> select)
    unsigned* pkey = (unsigned*)d_out;

    hipLaunchKernelGGL(p1_transpose, dim3(BB * NN / 256), dim3(256), 0, stream,
                       features, pT, sq32, sq64, pTh, pTl,
                       W1, W2, W3, W4, W5, g1, g2, g3, g4, g5,
                       Aw, Bw, w1d, W2s, W3p, W4p, W5b);
    hipLaunchKernelGGL(knn_prefilter, dim3(BB * NN / 32, 5), dim3(256), 0, stream,
                       pTh, pTl, sq32, pkey, pT, Aw, Bw, ctrA, nbrB);
    hipLaunchKernelGGL(knn_select, dim3(BB * NN / 64), dim3(512), 0, stream,
                       pT, sq64, pkey, fidx, fdist);
    hipLaunchKernelGGL(fuse_kernel, dim3(BB * NN * KK / 64), dim3(64), 0, stream,
                       coords, features, knn_idx, knn_dist, W2s, W3p, W4p, W5b,
                       b1, b2, b3, b4, b5,
                       ctrA, nbrB, w1d, fidx, fdist, out);
}

// Round 30
// 135.560 us; speedup vs baseline: 1.6733x; 1.6733x over previous
//
#include <hip/hip_runtime.h>
#include <math.h>

#define BB 4
#define NN 4096
#define KK 16
#define CIN 32
#define BN_INV 0.9999950000375f

#define RS 32    // candidate ranges per query (128 candidates each)
#define PK 8     // prefilter top-K per range
#define TSL 16   // per-wave-slice forwarded top keys
#define NSURV 24 // global fp32-key survivors reranked in fp64
#define NSL 8    // wave-slices in knn_select (4 ranges each)

typedef float f32x2 __attribute__((ext_vector_type(2)));
typedef float f32x16v __attribute__((ext_vector_type(16)));
typedef short bf16x8 __attribute__((ext_vector_type(8)));
typedef unsigned long long u64;

__device__ __forceinline__ u64 u64min(u64 a, u64 b) { return a < b ? a : b; }
__device__ __forceinline__ u64 u64max(u64 a, u64 b) { return a > b ? a : b; }
__device__ __forceinline__ unsigned short f2bf(float x) {
    unsigned u = __float_as_uint(x);
    unsigned r = u + 0x7FFFu + ((u >> 16) & 1u);  // RNE
    return (unsigned short)(r >> 16);
}

// Merge sorted pair {keys of DX,DY} into sorted-desc K[0..7] keeping top-8.
#define KMERGE2(K, DX, DY, MK0, MK1)                                                  \
    {                                                                                 \
        unsigned uA_ = ~__float_as_uint(DX);                                          \
        unsigned uB_ = ~__float_as_uint(DY);                                          \
        unsigned kA_ = (uA_ & 0xFFFFF000u) | (unsigned)(MK0);                         \
        unsigned kB_ = (uB_ & 0xFFFFF000u) | (unsigned)(MK1);                         \
        unsigned P0_ = __builtin_elementwise_max(kA_, kB_);                           \
        unsigned P1_ = __builtin_elementwise_min(kA_, kB_);                           \
        unsigned mp0_[7], mp1_[6];                                                    \
        _Pragma("unroll")                                                             \
        for (int j_ = 0; j_ < 7; ++j_) mp0_[j_] = __builtin_elementwise_min(K[j_], P0_); \
        _Pragma("unroll")                                                             \
        for (int j_ = 0; j_ < 6; ++j_) mp1_[j_] = __builtin_elementwise_min(K[j_], P1_); \
        unsigned R_[8];                                                               \
        R_[0] = __builtin_elementwise_max(K[0], P0_);                                 \
        R_[1] = __builtin_elementwise_max(__builtin_elementwise_max(K[1], mp0_[0]), P1_); \
        _Pragma("unroll")                                                             \
        for (int j_ = 2; j_ < 8; ++j_)                                                \
            R_[j_] = __builtin_elementwise_max(                                       \
                __builtin_elementwise_max(K[j_], mp0_[j_ - 1]), mp1_[j_ - 2]);        \
        _Pragma("unroll")                                                             \
        for (int j_ = 0; j_ < 8; ++j_) K[j_] = R_[j_];                                \
    }

// ---------------- P1 (+P0 folded): transpose + norms + bf16 splits + weights ----------
__global__ void p1_transpose(const float* __restrict__ f, float* __restrict__ pT,
                             float* __restrict__ sq32, double* __restrict__ sq64,
                             unsigned short* __restrict__ pTh,
                             unsigned short* __restrict__ pTl,
                             const float* __restrict__ W1, const float* __restrict__ W2,
                             const float* __restrict__ W3, const float* __restrict__ W4,
                             const float* __restrict__ W5,
                             const float* __restrict__ g1, const float* __restrict__ g2,
                             const float* __restrict__ g3, const float* __restrict__ g4,
                             const float* __restrict__ g5,
                             float* __restrict__ Aw, float* __restrict__ Bw,
                             float* __restrict__ w1d, float* __restrict__ W2s,
                             float* __restrict__ W3p, float* __restrict__ W4p,
                             unsigned short* __restrict__ W5b) {
    int t = threadIdx.x;
    if (blockIdx.x == 0) {  // weight prep (former p0)
        for (int i = t; i < 64 * 32; i += 256) {
            int o = i >> 5, c = i & 31;
            float s = g1[o] * BN_INV;
            Aw[i] = (W1[o * 128 + c] - W1[o * 128 + 64 + c]) * s;
            Bw[i] = (W1[o * 128 + 32 + c] + W1[o * 128 + 64 + c]) * s;
        }
        if (t < 64) {
            float s = 0.f;
            for (int c = 96; c < 128; ++c) s += W1[t * 128 + c];
            w1d[t] = s * (g1[t] * BN_INV);
        }
        for (int i = t; i < 192; i += 256) W2s[i] = W2[i] * (g2[i / 64] * BN_INV);
        for (int i = t; i < 32 * 14; i += 256) {
            int r = i / 14, j = i - r * 14;
            W3p[i] = (j < 13) ? W3[r * 13 + j] * (g3[r] * BN_INV) : 0.f;
            W4p[i] = (j < 13) ? W4[r * 13 + j] * (g4[r] * BN_INV) : 0.f;
        }
        for (int i = t; i < 3072; i += 256)
            W5b[i] = f2bf(W5[i] * (g5[i / 96] * BN_INV));
    }
    int g = blockIdx.x * 256 + t;  // b*N + n
    int b = g >> 12, n = g & (NN - 1);
    float v[CIN];
#pragma unroll
    for (int c = 0; c < CIN; ++c) v[c] = f[(b * CIN + c) * NN + n];
#pragma unroll
    for (int c = 0; c < CIN; ++c) pT[(size_t)g * CIN + c] = v[c];
    // bf16 hi/lo split for the MFMA prefilter
#pragma unroll
    for (int c = 0; c < CIN; ++c) {
        unsigned short h = f2bf(v[c]);
        float hf = __uint_as_float((unsigned)h << 16);
        pTh[(size_t)g * CIN + c] = h;
        pTl[(size_t)g * CIN + c] = f2bf(v[c] - hf);
    }
    float s32 = 0.f;
#pragma unroll
    for (int c = 0; c < CIN; ++c) s32 = fmaf(v[c], v[c], s32);
    sq32[g] = s32;
    // sequential fp64 chain — must match knn_select's rerank chains
    double s64 = 0.0;
#pragma unroll
    for (int c = 0; c < CIN; ++c) s64 = fma((double)v[c], (double)v[c], s64);
    sq64[g] = s64;
}

// ---------------- KNN prefilter (MFMA) + fused p2 slice (blockIdx.y == 4) -------------
__global__ __launch_bounds__(256) void knn_prefilter(const unsigned short* __restrict__ pTh,
                                                     const unsigned short* __restrict__ pTl,
                                                     const float* __restrict__ sq32,
                                                     unsigned* __restrict__ pkey,
                                                     const float* __restrict__ pT,
                                                     const float* __restrict__ Aw,
                                                     const float* __restrict__ Bw,
                                                     float* __restrict__ ctrA,
                                                     float* __restrict__ nbrB) {
    __shared__ float sAB[2][2048];  // 16 KB, used only by the p2 slice
    if (blockIdx.y == 4) {
        // p2: per-point projections ctrA = A*p, nbrB = B*p (pre-scaled weights)
        float* sA = sAB[0];
        float* sB = sAB[1];
        for (int i = threadIdx.x; i < 2048; i += 256) {
            int o = i >> 5, c = i & 31;
            sA[c * 64 + o] = Aw[i];
            sB[c * 64 + o] = Bw[i];
        }
        __syncthreads();
#pragma unroll 1
        for (int it = 0; it < 8; ++it) {
            int g = (blockIdx.x * 8 + it) * 256 + threadIdx.x;  // (b*N+n)*64 + o
            int o = g & 63;
            int pn = g >> 6;
            const float* p = pT + (size_t)pn * 32;
            float a = 0.f, bb = 0.f;
#pragma unroll
            for (int c = 0; c < 32; ++c) {
                float pv = p[c];
                a = fmaf(sA[c * 64 + o], pv, a);
                bb = fmaf(sB[c * 64 + o], pv, bb);
            }
            ctrA[g] = a;
            nbrB[g] = bb;
        }
        return;
    }

    int lane = threadIdx.x & 63;
    int wave = threadIdx.x >> 6;        // 0..3
    int ws = wave + 4 * blockIdx.y;     // range slot 0..15 (2 ranges of 128 each)
    int qtile = blockIdx.x;             // 0..511
    int pn = qtile * 32 + (lane & 31);  // this lane's query (global point id)
    int b = pn >> 12;
    int bbase = b << 12;
    int koff = (lane >> 5) * 8;

    const unsigned short* qh = pTh + (size_t)pn * 32;
    const unsigned short* ql = pTl + (size_t)pn * 32;
    bf16x8 bh0 = *(const bf16x8*)(qh + koff);
    bf16x8 bh1 = *(const bf16x8*)(qh + 16 + koff);
    bf16x8 bl0 = *(const bf16x8*)(ql + koff);
    bf16x8 bl1 = *(const bf16x8*)(ql + 16 + koff);
    float sqq = sq32[pn];

    for (int r = ws * 2; r < ws * 2 + 2; ++r) {
        unsigned key[PK];
#pragma unroll
        for (int i = 0; i < PK; ++i) key[i] = 0u;
#pragma unroll
        for (int tile = 0; tile < 4; ++tile) {
            int cb = r * 128 + tile * 32;                // candidate base within batch
            int crow = bbase + cb + (lane & 31);
            const unsigned short* ah = pTh + (size_t)crow * 32;
            const unsigned short* al = pTl + (size_t)crow * 32;
            bf16x8 a_h0 = *(const bf16x8*)(ah + koff);
            bf16x8 a_h1 = *(const bf16x8*)(ah + 16 + koff);
            bf16x8 a_l0 = *(const bf16x8*)(al + koff);
            bf16x8 a_l1 = *(const bf16x8*)(al + 16 + koff);
            f32x16v acc = {};
            acc = __builtin_amdgcn_mfma_f32_32x32x16_bf16(a_h0, bh0, acc, 0, 0, 0);
            acc = __builtin_amdgcn_mfma_f32_32x32x16_bf16(a_h1, bh1, acc, 0, 0, 0);
            acc = __builtin_amdgcn_mfma_f32_32x32x16_bf16(a_h0, bl0, acc, 0, 0, 0);
            acc = __builtin_amdgcn_mfma_f32_32x32x16_bf16(a_h1, bl1, acc, 0, 0, 0);
            acc = __builtin_amdgcn_mfma_f32_32x32x16_bf16(a_l0, bh0, acc, 0, 0, 0);
            acc = __builtin_amdgcn_mfma_f32_32x32x16_bf16(a_l1, bh1, acc, 0, 0, 0);
            int rb = bbase + cb + 4 * (lane >> 5);
            float4 s0 = *(const float4*)(sq32 + rb);
            float4 s1 = *(const float4*)(sq32 + rb + 8);
            float4 s2 = *(const float4*)(sq32 + rb + 16);
            float4 s3 = *(const float4*)(sq32 + rb + 24);
            float sarr[16] = {s0.x, s0.y, s0.z, s0.w, s1.x, s1.y, s1.z, s1.w,
                              s2.x, s2.y, s2.z, s2.w, s3.x, s3.y, s3.z, s3.w};
#pragma unroll
            for (int j = 0; j < 16; j += 2) {
                float d0 = fmaf(2.f, acc[j], -(sqq + sarr[j]));
                float d1 = fmaf(2.f, acc[j + 1], -(sqq + sarr[j + 1]));
                int mk0 = 4095 - (cb + (j & 3) + 8 * (j >> 2) + 4 * (lane >> 5));
                KMERGE2(key, d0, d1, mk0, mk0 - 1)
            }
        }
        unsigned ok[PK];
#pragma unroll
        for (int i = 0; i < PK; ++i) ok[i] = __shfl(key[i], lane ^ 32, 64);
        unsigned R[PK];
#pragma unroll
        for (int j = 0; j < PK; ++j) {
            unsigned m = __builtin_elementwise_max(key[j], ok[j]);
#pragma unroll
            for (int a = 0; a < j; ++a)
                m = __builtin_elementwise_max(
                    m, __builtin_elementwise_min(key[a], ok[j - 1 - a]));
            R[j] = m;
        }
        if (lane < 32) {
#pragma unroll
            for (int i = 0; i < PK; ++i)
                pkey[(size_t)(r * PK + i) * (BB * NN) + pn] = R[i];
        }
    }
}

// ---------------- KNN select: 512 thr, 8 slices of 4 ranges; -> top-24 -> fp64 ---------
__global__ __launch_bounds__(512) void knn_select(const float* __restrict__ pT,
                                                  const double* __restrict__ sq64,
                                                  const unsigned* __restrict__ pkey,
                                                  int* __restrict__ fidx,
                                                  float* __restrict__ fdist) {
    __shared__ unsigned sA[NSL][64][TSL];   // 32 KB
    __shared__ unsigned sCand[64][NSURV];   // 6 KB
    __shared__ u64 sKl[NSL][64][3];         // 12 KB
    int tid = threadIdx.x;
    int q = tid & 63;
    int w = tid >> 6;                       // 0..7
    int n = blockIdx.x * 64 + q;
    int b = n >> 12;

    // Phase A: scan ranges [4w,4w+4) -> top-TSL fp32 keys (coalesced, early-break)
    unsigned sk[TSL];
#pragma unroll
    for (int i = 0; i < TSL; ++i) sk[i] = 0u;
#pragma unroll 1
    for (int r = w * 4; r < w * 4 + 4; ++r) {
        unsigned kv[PK];
#pragma unroll
        for (int k = 0; k < PK; ++k)
            kv[k] = pkey[(size_t)(r * PK + k) * (BB * NN) + n];
        for (int k = 0; k < PK; ++k) {
            unsigned cv = kv[k];
            if (__all(cv <= sk[TSL - 1])) break;  // range keys sorted desc
#pragma unroll
            for (int j = 0; j < TSL; ++j) {
                unsigned vj = sk[j];
                sk[j] = __builtin_elementwise_max(cv, vj);
                cv = __builtin_elementwise_min(cv, vj);
            }
        }
    }
#pragma unroll
    for (int i = 0; i < TSL; ++i) sA[w][q][i] = sk[i];
    __syncthreads();

    // Phase B: merge NSL sorted-TSL lists -> global top-NSURV candidate ids
    if (tid < 64) {
        unsigned R[NSURV];
#pragma unroll
        for (int i = 0; i < NSURV; ++i) R[i] = (i < TSL) ? sA[0][tid][i] : 0u;
#pragma unroll 1
        for (int wv = 1; wv < NSL; ++wv) {
            unsigned L[TSL];
#pragma unroll
            for (int i = 0; i < TSL; ++i) L[i] = sA[wv][tid][i];
            unsigned Rn[NSURV];
#pragma unroll
            for (int j = 0; j < NSURV; ++j) {
                unsigned m = R[j];
                if (j < TSL) m = __builtin_elementwise_max(m, L[j]);
#pragma unroll
                for (int t = 0; t < NSURV; ++t) {
                    if (t < j && t < TSL) {
                        m = __builtin_elementwise_max(
                            m, __builtin_elementwise_min(R[j - 1 - t], L[t]));
                    }
                }
                Rn[j] = m;
            }
#pragma unroll
            for (int j = 0; j < NSURV; ++j) R[j] = Rn[j];
        }
#pragma unroll
        for (int i = 0; i < NSURV; ++i) sCand[tid][i] = 4095u - (R[i] & 0xFFFu);
    }
    __syncthreads();

    // Phase C: fp64 rerank — thread (q,w) handles survivors w, w+8, w+16 (3 each)
    {
        const float* pb = pT + ((size_t)(b << 12)) * 32;
        const double* sqb = sq64 + (b << 12);
        double qv[32];
        const float4* q4 = (const float4*)(pT + (size_t)n * 32);
#pragma unroll
        for (int c4 = 0; c4 < 8; ++c4) {
            float4 t = q4[c4];
            qv[4 * c4] = (double)t.x; qv[4 * c4 + 1] = (double)t.y;
            qv[4 * c4 + 2] = (double)t.z; qv[4 * c4 + 3] = (double)t.w;
        }
        double sqn = 0.0;
#pragma unroll
        for (int c = 0; c < 32; ++c) sqn = fma(qv[c], qv[c], sqn);

        u64 kl[3];
#pragma unroll
        for (int i = 0; i < 3; ++i) kl[i] = 0ull;
#pragma unroll
        for (int i = 0; i < 3; ++i) {
            int m = (int)sCand[q][w + NSL * i];
            const float4* row = (const float4*)(pb + (size_t)m * 32);
            double dot = 0.0;
#pragma unroll
            for (int c4 = 0; c4 < 8; ++c4) {
                float4 t = row[c4];
                dot = fma((double)t.x, qv[4 * c4], dot);
                dot = fma((double)t.y, qv[4 * c4 + 1], dot);
                dot = fma((double)t.z, qv[4 * c4 + 2], dot);
                dot = fma((double)t.w, qv[4 * c4 + 3], dot);
            }
            double d = 2.0 * dot - sqn - sqb[m];  // self -> exactly 0
            long long bits = __double_as_longlong(d);
            u64 m64 = (bits < 0) ? ~(u64)bits : ((u64)bits | 0x8000000000000000ull);
            u64 cv = (m64 & ~0xFFFull) | (unsigned)m;  // pack idx in low 12 bits
#pragma unroll
            for (int j = 0; j < 3; ++j) {
                u64 vj = kl[j];
                kl[j] = u64max(cv, vj);
                cv = u64min(cv, vj);
            }
        }
#pragma unroll
        for (int i = 0; i < 3; ++i) sKl[w][q][i] = kl[i];
    }
    __syncthreads();

    // Phase D: merge NSL sorted-3 u64 lists -> exact top-16; write outputs
    if (tid < 64) {
        u64 R[16];
#pragma unroll
        for (int i = 0; i < 16; ++i) R[i] = (i < 3) ? sKl[0][tid][i] : 0ull;
#pragma unroll 1
        for (int wv = 1; wv < NSL; ++wv) {
            u64 L[3];
#pragma unroll
            for (int i = 0; i < 3; ++i) L[i] = sKl[wv][tid][i];
            u64 Rn[16];
#pragma unroll
            for (int j = 0; j < 16; ++j) {
                u64 m = R[j];
                if (j < 3) m = u64max(m, L[j]);
#pragma unroll
                for (int t = 0; t < 3; ++t) {
                    if (t < j) m = u64max(m, u64min(R[j - 1 - t], L[t]));
                }
                Rn[j] = m;
            }
#pragma unroll
            for (int j = 0; j < 16; ++j) R[j] = Rn[j];
        }
        int nq = blockIdx.x * 64 + tid;
#pragma unroll
        for (int i = 0; i < 16; ++i) {
            u64 m64 = R[i];
            long long bits = (m64 & 0x8000000000000000ull)
                                 ? (long long)(m64 ^ 0x8000000000000000ull)
                                 : (long long)~m64;
            fdist[(size_t)nq * 16 + i] = (float)__longlong_as_double(bits);
            fidx[(size_t)nq * 16 + i] = (int)(m64 & 0xFFFull);
        }
    }
}

// ---------------- Fused pipeline: 64-thr blocks (1 wave); W5 via MFMA 3-phase LDS ------
__global__ __launch_bounds__(64, 4) void fuse_kernel(
    const float* __restrict__ coords, const float* __restrict__ feat,
    const int* __restrict__ knn_idx, const float* __restrict__ knn_dist,
    const float* __restrict__ W2s, const float* __restrict__ W3p,
    const float* __restrict__ W4p, const unsigned short* __restrict__ W5b,
    const float* __restrict__ b1, const float* __restrict__ b2,
    const float* __restrict__ b3, const float* __restrict__ b4,
    const float* __restrict__ b5,
    const float* __restrict__ ctrA, const float* __restrict__ nbrB,
    const float* __restrict__ w1d, const int* __restrict__ fidx,
    const float* __restrict__ fdist, float* __restrict__ out) {
    __shared__ unsigned short xbuf[64][36];  // 4.6 KB: 32-col phase tile (wave-local)
    int ln = threadIdx.x;                    // 0..63, one wave per block
    int g = blockIdx.x * 64 + ln;
    int k = g & 15;
    int n = (g >> 4) & (NN - 1);
    int b = g >> 16;
    int pn = b * NN + n;

    // coalesced per-(n,k) gathers
    int fnb = fidx[(size_t)pn * 16 + k];
    float fd = fdist[(size_t)pn * 16 + k];
    int cnb = knn_idx[(size_t)pn * 16 + k];
    float kd = knn_dist[(size_t)pn * 16 + k];
    const float4* nB4 = (const float4*)(nbrB + ((size_t)b * NN + fnb) * 64);
    const float4* cA4 = (const float4*)(ctrA + (size_t)pn * 64);
    float cq[3], cn_[3];
#pragma unroll
    for (int j = 0; j < 3; ++j) cq[j] = coords[(size_t)pn * 3 + j];
#pragma unroll
    for (int j = 0; j < 3; ++j) cn_[j] = coords[((size_t)b * NN + cnb) * 3 + j];

    // features_knn (64): fk = max(v, 0.2v), v = cA' + nB' + w1d'*fd + b1 (scales pre-folded)
    const f32x2* wd2 = (const f32x2*)w1d;
    const f32x2* b12 = (const f32x2*)b1;
    f32x2 fdp = (f32x2){fd, fd};
    f32x2 pt2 = (f32x2){0.2f, 0.2f};
    f32x2 fkp[32];
#pragma unroll
    for (int half = 0; half < 2; ++half) {
        float4 nbh[8];
#pragma unroll
        for (int i = 0; i < 8; ++i) nbh[i] = nB4[8 * half + i];  // batched gather
#pragma unroll
        for (int j = 0; j < 8; ++j) {
            int o4 = 8 * half + j;
            float4 nb = nbh[j];
            float4 ca = cA4[o4];
            f32x2 s01 = (f32x2){ca.x, ca.y} + (f32x2){nb.x, nb.y};
            f32x2 s23 = (f32x2){ca.z, ca.w} + (f32x2){nb.z, nb.w};
            f32x2 v0 = __builtin_elementwise_fma(wd2[2 * o4 + 0], fdp, s01) + b12[2 * o4 + 0];
            f32x2 v1 = __builtin_elementwise_fma(wd2[2 * o4 + 1], fdp, s23) + b12[2 * o4 + 1];
            fkp[2 * o4 + 0] = __builtin_elementwise_max(v0, v0 * pt2);
            fkp[2 * o4 + 1] = __builtin_elementwise_max(v1, v1 * pt2);
        }
    }

    // batch-issue feat loads early
    float fadd[32];
#pragma unroll
    for (int c = 0; c < 32; ++c) fadd[c] = feat[((size_t)b * 32 + c) * NN + n];

    // features_offset (3) = elu(W2s . fk + b2); 4-acc ILP dot
    f32x2 cpp[7];
    float pe[3];
#pragma unroll
    for (int j = 0; j < 3; ++j) {
        const f32x2* w2r = (const f32x2*)(W2s + j * 64);
        f32x2 a0 = (f32x2){0.f, 0.f}, a1 = (f32x2){0.f, 0.f};
        f32x2 a2 = (f32x2){0.f, 0.f}, a3 = (f32x2){0.f, 0.f};
#pragma unroll
        for (int i = 0; i < 8; ++i) {
            a0 = __builtin_elementwise_fma(w2r[4 * i + 0], fkp[4 * i + 0], a0);
            a1 = __builtin_elementwise_fma(w2r[4 * i + 1], fkp[4 * i + 1], a1);
            a2 = __builtin_elementwise_fma(w2r[4 * i + 2], fkp[4 * i + 2], a2);
            a3 = __builtin_elementwise_fma(w2r[4 * i + 3], fkp[4 * i + 3], a3);
        }
        f32x2 ap = (a0 + a1) + (a2 + a3);
        float t = (ap.x + ap.y) + b2[j];
        t = t > 0.f ? t : __expf(t) - 1.f;
        pe[j] = t + cq[j];
    }
    cpp[0] = (f32x2){cq[0], cq[1]};
    cpp[1] = (f32x2){cq[2], cn_[0]};
    cpp[2] = (f32x2){cn_[1], cn_[2]};
    cpp[3] = (f32x2){cq[0] - cn_[0], cq[1] - cn_[1]};
    cpp[4] = (f32x2){cq[2] - cn_[2], kd};
    cpp[5] = (f32x2){pe[0], pe[1]};
    cpp[6] = (f32x2){pe[2], 0.f};

    // point_offset -> features_e ; out_point (unrolled: fep writes must be static)
    size_t outbase = (((size_t)b * 64) * NN + n) * 16 + k;  // c stride NN*16
    f32x2 fep[16];
#pragma unroll
    for (int c2 = 0; c2 < 16; ++c2) {
        float fv[2];
#pragma unroll
        for (int h = 0; h < 2; ++h) {
            int c = 2 * c2 + h;
            const f32x2* w3r = (const f32x2*)(W3p + c * 14);
            const f32x2* w4r = (const f32x2*)(W4p + c * 14);
            f32x2 a3p = (f32x2){0.f, 0.f}, a4p = (f32x2){0.f, 0.f};
#pragma unroll
            for (int j = 0; j < 7; ++j) {
                a3p = __builtin_elementwise_fma(w3r[j], cpp[j], a3p);
                a4p = __builtin_elementwise_fma(w4r[j], cpp[j], a4p);
            }
            float po = (a3p.x + a3p.y) + b3[c];
            po = po > 0.f ? po : __expf(po) - 1.f;
            fv[h] = po + fadd[c];
            float op = (a4p.x + a4p.y) + b4[c];
            op = op > 0.f ? op : __expf(op) - 1.f;
            out[outbase + (size_t)c * (NN * 16)] = op;
        }
        fep[c2] = (f32x2){fv[0], fv[1]};
    }

    // W5 via MFMA in 3 wave-local phases (one wave per block; lockstep LDS, no barrier).
    {
        int koff = (ln >> 5) * 8;
        unsigned* row32 = (unsigned*)&xbuf[ln][0];
        f32x16v acc0 = {}, acc1 = {};
#pragma unroll
        for (int ph = 0; ph < 3; ++ph) {
#pragma unroll
            for (int i = 0; i < 16; ++i) {
                f32x2 src = (ph == 0) ? fkp[i] : (ph == 1) ? fkp[16 + i] : fep[i];
                unsigned u0 = __float_as_uint(src.x);
                unsigned u1 = __float_as_uint(src.y);
                row32[i] = (u0 >> 16) | (u1 & 0xFFFF0000u);
            }
#pragma unroll
            for (int c2 = 0; c2 < 2; ++c2) {
                int ch = ph * 2 + c2;
                bf16x8 aw = *(const bf16x8*)(W5b + (ln & 31) * 96 + ch * 16 + koff);
                bf16x8 bx0 = *(const bf16x8*)(&xbuf[ln & 31][c2 * 16 + koff]);
                bf16x8 bx1 = *(const bf16x8*)(&xbuf[32 + (ln & 31)][c2 * 16 + koff]);
                acc0 = __builtin_amdgcn_mfma_f32_32x32x16_bf16(aw, bx0, acc0, 0, 0, 0);
                acc1 = __builtin_amdgcn_mfma_f32_32x32x16_bf16(aw, bx1, acc1, 0, 0, 0);
            }
        }
#pragma unroll
        for (int tile = 0; tile < 2; ++tile) {
            int p = tile * 32 + (ln & 31);
            int gg = blockIdx.x * 64 + p;
            int kk = gg & 15;
            int nn2 = (gg >> 4) & (NN - 1);
            int bb2 = gg >> 16;
            size_t obase = (((size_t)bb2 * 64 + 32) * NN + nn2) * 16 + kk;
            const f32x16v& acc = tile ? acc1 : acc0;
#pragma unroll
            for (int j = 0; j < 16; ++j) {
                int c = (j & 3) + 8 * (j >> 2) + 4 * (ln >> 5);
                float v = acc[j] + b5[c];
                v = v > 0.f ? v : __expf(v) - 1.f;
                out[obase + (size_t)c * (NN * 16)] = v;
            }
        }
    }
}

extern "C" void kernel_launch(void* const* d_in, const int* in_sizes, int n_in,
                              void* d_out, int out_size, void* d_ws, size_t ws_size,
                              hipStream_t stream) {
    const float* coords   = (const float*)d_in[0];
    const float* features = (const float*)d_in[1];
    const int*   knn_idx  = (const int*)d_in[2];
    const float* knn_dist = (const float*)d_in[3];
    const float* W1 = (const float*)d_in[4];
    const float* W2 = (const float*)d_in[5];
    const float* W3 = (const float*)d_in[6];
    const float* W4 = (const float*)d_in[7];
    const float* W5 = (const float*)d_in[8];
    const float* g1 = (const float*)d_in[9];
    const float* b1 = (const float*)d_in[10];
    const float* g2 = (const float*)d_in[11];
    const float* b2 = (const float*)d_in[12];
    const float* g3 = (const float*)d_in[13];
    const float* b3 = (const float*)d_in[14];
    const float* g4 = (const float*)d_in[15];
    const float* b4 = (const float*)d_in[16];
    const float* g5 = (const float*)d_in[17];
    const float* b5 = (const float*)d_in[18];
    float* out = (float*)d_out;

    // workspace layout (float slots)
    float*  pT    = (float*)d_ws;                  // 524288
    float*  sq32  = pT + BB * NN * 32;             // 16384
    double* sq64  = (double*)(sq32 + BB * NN);     // 16384 doubles (32768 slots)
    float*  fdist = (float*)(sq64 + BB * NN);      // 262144
    int*    fidx  = (int*)(fdist + BB * NN * 16);  // 262144
    float*  Aw    = (float*)(fidx + BB * NN * 16); // 2048
    float*  Bw    = Aw + 2048;                     // 2048
    float*  w1d   = Bw + 2048;                     // 64
    float*  W3p   = w1d + 64;                      // 448 (pad to 512)
    float*  W4p   = W3p + 512;                     // 448 (pad to 512)
    float*  W2s   = W4p + 512;                     // 192 (pad to 256)
    unsigned short* W5b = (unsigned short*)(W2s + 256);  // 3072 u16 (1536 slots)
    float*  ctrA  = W2s + 256 + 1536;              // B*N*64 = 1048576
    float*  nbrB  = ctrA + BB * NN * 64;           // B*N*64 = 1048576
    unsigned short* pTh = (unsigned short*)(nbrB + BB * NN * 64);  // B*N*32 u16
    unsigned short* pTl = pTh + (size_t)BB * NN * 32;              // B*N*32 u16
    // scratch in d_out (67.1 MB): pkey [RS*PK][B*N] u32 = 16.8 MB (prefilter -> select)
    unsigned* pkey = (unsigned*)d_out;

    hipLaunchKernelGGL(p1_transpose, dim3(BB * NN / 256), dim3(256), 0, stream,
                       features, pT, sq32, sq64, pTh, pTl,
                       W1, W2, W3, W4, W5, g1, g2, g3, g4, g5,
                       Aw, Bw, w1d, W2s, W3p, W4p, W5b);
    hipLaunchKernelGGL(knn_prefilter, dim3(BB * NN / 32, 5), dim3(256), 0, stream,
                       pTh, pTl, sq32, pkey, pT, Aw, Bw, ctrA, nbrB);
    hipLaunchKernelGGL(knn_select, dim3(BB * NN / 64), dim3(512), 0, stream,
                       pT, sq64, pkey, fidx, fdist);
    hipLaunchKernelGGL(fuse_kernel, dim3(BB * NN * KK / 64), dim3(64), 0, stream,
                       coords, features, knn_idx, knn_dist, W2s, W3p, W4p, W5b,
                       b1, b2, b3, b4, b5,
                       ctrA, nbrB, w1d, fidx, fdist, out);
}